// Round 1
// baseline (1107.637 us; speedup 1.0000x reference)
//
#include <hip/hip_runtime.h>
#include <stdint.h>

// ---------------------------------------------------------------------------
// InvariantPointAttention, N=20000 nodes, E=640000 edges, H=4, S=64, QK=VD=8
//
// Pipeline (all on `stream`):
//   k_zero   : zero CSR counts
//   k_count  : histogram edges by idx_i
//   k_scan   : exclusive scan -> row_off, cursor   (single block)
//   k_fill   : scatter edges into CSR order (sorted_i/j/e)
//   k_proj   : per-node projections:
//                q_s,k_s (bf16, N x 256), q_v,k_v (rotated+translated, bf16 Nx96)
//                v_s (f32 N x 256), v_loc (raw points f32 N x 96)
//              NOTE: out_scalar == v_s and out_vec == raw v_loc exactly
//              (softmax weights sum to 1; R^-1(R(v)+t-t)=v), so v needs no
//              rotation and no edge aggregation.
//   k_edge   : per sorted edge: logits[4] (f32) + pair_z[16] (bf16), coalesced
//   k_soft   : per (node,head): two-pass softmax over CSR segment ->
//              normalized out_pair (N x 64 f32).  No atomics.
//   k_out    : assemble feats[448] per node + feats @ Wout + bout -> out
// ---------------------------------------------------------------------------

#define C_SQRT83  1.6329931618554518f   // sqrt(8/3)
#define C_SQRT13  0.5773502691896258f   // sqrt(1/3)
#define C_VEC    -0.04811252243246881f  // -0.5*sqrt(1/108)

__device__ __forceinline__ unsigned short f2bf(float f){
  unsigned u = __float_as_uint(f);
  u += 0x7fffu + ((u >> 16) & 1u);          // round-to-nearest-even
  return (unsigned short)(u >> 16);
}
__device__ __forceinline__ unsigned pack2(float a, float b){
  return (unsigned)f2bf(a) | ((unsigned)f2bf(b) << 16);
}
__device__ __forceinline__ float bflo(unsigned u){ return __uint_as_float(u << 16); }
__device__ __forceinline__ float bfhi(unsigned u){ return __uint_as_float(u & 0xffff0000u); }

__device__ __forceinline__ void quat_rot(float w, float ux, float uy, float uz,
                                         float vx, float vy, float vz,
                                         float& ox, float& oy, float& oz){
  float cx = uy*vz - uz*vy;
  float cy = uz*vx - ux*vz;
  float cz = ux*vy - uy*vx;
  float dx = uy*cz - uz*cy;
  float dy = uz*cx - ux*cz;
  float dz = ux*cy - uy*cx;
  ox = vx + 2.f*(w*cx + dx);
  oy = vy + 2.f*(w*cy + dy);
  oz = vz + 2.f*(w*cz + dz);
}

// -------------------------------- CSR build --------------------------------

__global__ __launch_bounds__(256) void k_zero(unsigned* __restrict__ counts, int n){
  int g = blockIdx.x*256 + threadIdx.x;
  if (g < n) counts[g] = 0u;
}

__global__ __launch_bounds__(256) void k_count(const int* __restrict__ ei,
                                               unsigned* __restrict__ counts, int ne){
  int e = blockIdx.x*256 + threadIdx.x;
  if (e >= ne) return;
  atomicAdd(&counts[ei[e]], 1u);
}

__global__ __launch_bounds__(256) void k_scan(const unsigned* __restrict__ counts,
                                              unsigned* __restrict__ row_off,
                                              unsigned* __restrict__ cursor, int n){
  __shared__ unsigned part[256];
  int t = threadIdx.x;
  int chunk = (n + 255) >> 8;
  int s0 = t*chunk, s1 = min(s0 + chunk, n);
  unsigned sum = 0;
  for (int k = s0; k < s1; ++k) sum += counts[k];
  part[t] = sum; __syncthreads();
  for (int off = 1; off < 256; off <<= 1){
    unsigned v = (t >= off) ? part[t-off] : 0u;
    __syncthreads();
    part[t] += v;
    __syncthreads();
  }
  unsigned run = (t == 0) ? 0u : part[t-1];
  for (int k = s0; k < s1; ++k){
    row_off[k] = run; cursor[k] = run; run += counts[k];
  }
  if (t == 255) row_off[n] = part[255];
}

__global__ __launch_bounds__(256) void k_fill(const int* __restrict__ ei,
                                              unsigned* __restrict__ cursor,
                                              unsigned* __restrict__ si,
                                              unsigned* __restrict__ sj,
                                              unsigned* __restrict__ se, int ne){
  int e = blockIdx.x*256 + threadIdx.x;
  if (e >= ne) return;
  int i = ei[e];
  unsigned pos = atomicAdd(&cursor[i], 1u);
  si[pos] = (unsigned)i;
  sj[pos] = (unsigned)ei[ne + e];
  se[pos] = (unsigned)e;
}

// ------------------------------ node projections ----------------------------

__device__ __forceinline__ void projCols256(const float* __restrict__ W, int col,
                                            const float* __restrict__ sarr, float out[4]){
  float a0=0.f,a1=0.f,a2=0.f,a3=0.f;
  #pragma unroll
  for (int k = 0; k < 64; ++k){
    const float4 wv = *(const float4*)(W + (size_t)k*256 + col);
    const float sk = sarr[k];
    a0 += sk*wv.x; a1 += sk*wv.y; a2 += sk*wv.z; a3 += sk*wv.w;
  }
  out[0]=a0; out[1]=a1; out[2]=a2; out[3]=a3;
}

__device__ __forceinline__ void projPts(const float* __restrict__ W, int p0,
                                        const float* __restrict__ sarr,
                                        float ax[4], float ay[4], float az[4]){
  #pragma unroll
  for (int c=0;c<4;c++){ ax[c]=0.f; ay[c]=0.f; az[c]=0.f; }
  #pragma unroll
  for (int k = 0; k < 64; ++k){
    const float* Wr = W + (size_t)k*96 + p0;
    const float4 wx = *(const float4*)(Wr);
    const float4 wy = *(const float4*)(Wr + 32);
    const float4 wz = *(const float4*)(Wr + 64);
    const float sk = sarr[k];
    ax[0]+=sk*wx.x; ax[1]+=sk*wx.y; ax[2]+=sk*wx.z; ax[3]+=sk*wx.w;
    ay[0]+=sk*wy.x; ay[1]+=sk*wy.y; ay[2]+=sk*wy.z; ay[3]+=sk*wy.w;
    az[0]+=sk*wz.x; az[1]+=sk*wz.y; az[2]+=sk*wz.z; az[3]+=sk*wz.w;
  }
}

__global__ __launch_bounds__(256) void k_proj(
    const float* __restrict__ s, const float* __restrict__ quat, const float* __restrict__ trans,
    const float* __restrict__ Wqs, const float* __restrict__ Wks, const float* __restrict__ Wvs,
    const float* __restrict__ Wqv, const float* __restrict__ Wkv, const float* __restrict__ Wvv,
    unsigned* __restrict__ qs, unsigned* __restrict__ ks, float* __restrict__ vs,
    unsigned* __restrict__ qv, unsigned* __restrict__ kv, float* __restrict__ vv, int n)
{
  const int lane = threadIdx.x & 63;
  const int wave = threadIdx.x >> 6;
  const int g = blockIdx.x*64 + lane;
  if (g >= n) return;

  float sarr[64];
  const float4* sr = (const float4*)(s + (size_t)g*64);
  #pragma unroll
  for (int k = 0; k < 16; ++k){
    float4 v = sr[k];
    sarr[4*k]=v.x; sarr[4*k+1]=v.y; sarr[4*k+2]=v.z; sarr[4*k+3]=v.w;
  }

  // scalar projections: 64 col-groups of 4 per matrix, 16 per wave
  for (int it = 0; it < 16; ++it){
    const int col = (it*4 + wave)*4;
    float o[4];
    projCols256(Wqs, col, sarr, o);
    { unsigned* d = qs + (size_t)g*128 + (col>>1);
      uint2 u; u.x = pack2(o[0],o[1]); u.y = pack2(o[2],o[3]); *(uint2*)d = u; }
    projCols256(Wks, col, sarr, o);
    { unsigned* d = ks + (size_t)g*128 + (col>>1);
      uint2 u; u.x = pack2(o[0],o[1]); u.y = pack2(o[2],o[3]); *(uint2*)d = u; }
    projCols256(Wvs, col, sarr, o);
    { float4 f; f.x=o[0]; f.y=o[1]; f.z=o[2]; f.w=o[3];
      *(float4*)(vs + (size_t)g*256 + col) = f; }
  }

  // vector projections: 8 point-groups of 4 per matrix, 2 per wave
  const float4 q4 = *(const float4*)(quat + (size_t)g*4);
  const float qw = q4.x, qx = q4.y, qy = q4.z, qz = q4.w;
  const float tx = trans[(size_t)g*3], ty = trans[(size_t)g*3+1], tz = trans[(size_t)g*3+2];

  for (int it = 0; it < 2; ++it){
    const int p0 = (it*4 + wave)*4;
    float ax[4], ay[4], az[4], rx[4], ry[4], rz[4];

    projPts(Wqv, p0, sarr, ax, ay, az);
    #pragma unroll
    for (int c=0;c<4;c++){
      quat_rot(qw,qx,qy,qz, ax[c],ay[c],az[c], rx[c],ry[c],rz[c]);
      rx[c]+=tx; ry[c]+=ty; rz[c]+=tz;
    }
    { unsigned* d = qv + (size_t)g*48 + (p0>>2)*6;
      uint2 u;
      u.x = pack2(rx[0],ry[0]); u.y = pack2(rz[0],rx[1]); *(uint2*)(d)   = u;
      u.x = pack2(ry[1],rz[1]); u.y = pack2(rx[2],ry[2]); *(uint2*)(d+2) = u;
      u.x = pack2(rz[2],rx[3]); u.y = pack2(ry[3],rz[3]); *(uint2*)(d+4) = u; }

    projPts(Wkv, p0, sarr, ax, ay, az);
    #pragma unroll
    for (int c=0;c<4;c++){
      quat_rot(qw,qx,qy,qz, ax[c],ay[c],az[c], rx[c],ry[c],rz[c]);
      rx[c]+=tx; ry[c]+=ty; rz[c]+=tz;
    }
    { unsigned* d = kv + (size_t)g*48 + (p0>>2)*6;
      uint2 u;
      u.x = pack2(rx[0],ry[0]); u.y = pack2(rz[0],rx[1]); *(uint2*)(d)   = u;
      u.x = pack2(ry[1],rz[1]); u.y = pack2(rx[2],ry[2]); *(uint2*)(d+2) = u;
      u.x = pack2(rz[2],rx[3]); u.y = pack2(ry[3],rz[3]); *(uint2*)(d+4) = u; }

    projPts(Wvv, p0, sarr, ax, ay, az);   // raw (pre-rotation) points == out_vec
    { float buf[12];
      #pragma unroll
      for (int c=0;c<4;c++){ buf[3*c]=ax[c]; buf[3*c+1]=ay[c]; buf[3*c+2]=az[c]; }
      float* d = vv + (size_t)g*96 + p0*3;
      *(float4*)(d)   = *(const float4*)(buf);
      *(float4*)(d+4) = *(const float4*)(buf+4);
      *(float4*)(d+8) = *(const float4*)(buf+8); }
  }
}

// ------------------------------- edge kernel -------------------------------

__global__ __launch_bounds__(256) void k_edge(
    const float* __restrict__ z,
    const unsigned* __restrict__ si, const unsigned* __restrict__ sj, const unsigned* __restrict__ se,
    const float* __restrict__ Wb,  const float* __restrict__ bb,
    const float* __restrict__ Wdz, const float* __restrict__ bdz,
    const float* __restrict__ hwts,
    const unsigned* __restrict__ qs, const unsigned* __restrict__ ks,
    const unsigned* __restrict__ qv, const unsigned* __restrict__ kv,
    float* __restrict__ logits, unsigned* __restrict__ pz, int ne)
{
  const int p = blockIdx.x*256 + threadIdx.x;
  if (p >= ne) return;
  const unsigned i = si[p], j = sj[p], e = se[p];

  // ---- bias (z@Wb) and pair (z@Wdz) ----
  float b4[4];  b4[0]=b4[1]=b4[2]=b4[3]=0.f;
  float pacc[16];
  #pragma unroll
  for (int c=0;c<16;c++) pacc[c]=0.f;
  const float* zr = z + (size_t)e*64;
  #pragma unroll
  for (int k4 = 0; k4 < 16; ++k4){
    const float4 zv = *(const float4*)(zr + 4*k4);
    #pragma unroll
    for (int kk = 0; kk < 4; ++kk){
      const int k = 4*k4 + kk;
      const float zk = (kk==0)?zv.x:((kk==1)?zv.y:((kk==2)?zv.z:zv.w));
      const float4 wb = *(const float4*)(Wb + k*4);
      b4[0]+=zk*wb.x; b4[1]+=zk*wb.y; b4[2]+=zk*wb.z; b4[3]+=zk*wb.w;
      const float* wd = Wdz + k*16;
      const float4 w0=*(const float4*)(wd), w1=*(const float4*)(wd+4),
                   w2=*(const float4*)(wd+8), w3=*(const float4*)(wd+12);
      pacc[ 0]+=zk*w0.x; pacc[ 1]+=zk*w0.y; pacc[ 2]+=zk*w0.z; pacc[ 3]+=zk*w0.w;
      pacc[ 4]+=zk*w1.x; pacc[ 5]+=zk*w1.y; pacc[ 6]+=zk*w1.z; pacc[ 7]+=zk*w1.w;
      pacc[ 8]+=zk*w2.x; pacc[ 9]+=zk*w2.y; pacc[10]+=zk*w2.z; pacc[11]+=zk*w2.w;
      pacc[12]+=zk*w3.x; pacc[13]+=zk*w3.y; pacc[14]+=zk*w3.z; pacc[15]+=zk*w3.w;
    }
  }
  #pragma unroll
  for (int c=0;c<16;c++) pacc[c] += bdz[c];
  { uint4 u0, u1;
    u0.x=pack2(pacc[0],pacc[1]);   u0.y=pack2(pacc[2],pacc[3]);
    u0.z=pack2(pacc[4],pacc[5]);   u0.w=pack2(pacc[6],pacc[7]);
    u1.x=pack2(pacc[8],pacc[9]);   u1.y=pack2(pacc[10],pacc[11]);
    u1.z=pack2(pacc[12],pacc[13]); u1.w=pack2(pacc[14],pacc[15]);
    uint4* d = (uint4*)(pz + (size_t)p*8);
    d[0]=u0; d[1]=u1; }

  // ---- scalar attention dot: k_s[i] . q_s[j] per head ----
  const uint4* kr = (const uint4*)(ks + (size_t)i*128);
  const uint4* qr = (const uint4*)(qs + (size_t)j*128);
  float sdot[4];
  #pragma unroll
  for (int h = 0; h < 4; ++h){
    float acc = 0.f;
    #pragma unroll
    for (int c = 0; c < 8; ++c){
      const uint4 a = kr[h*8+c];
      const uint4 b = qr[h*8+c];
      acc += bflo(a.x)*bflo(b.x) + bfhi(a.x)*bfhi(b.x);
      acc += bflo(a.y)*bflo(b.y) + bfhi(a.y)*bfhi(b.y);
      acc += bflo(a.z)*bflo(b.z) + bfhi(a.z)*bfhi(b.z);
      acc += bflo(a.w)*bflo(b.w) + bfhi(a.w)*bfhi(b.w);
    }
    sdot[h] = acc;
  }

  // ---- vector attention: sum_p |q_v[i]-k_v[j]|^2 per head ----
  const uint4* qvr = (const uint4*)(qv + (size_t)i*48);
  const uint4* kvr = (const uint4*)(kv + (size_t)j*48);
  float vsum[4];
  #pragma unroll
  for (int h = 0; h < 4; ++h){
    float acc = 0.f;
    #pragma unroll
    for (int c = 0; c < 3; ++c){
      const uint4 a = qvr[h*3+c];
      const uint4 b = kvr[h*3+c];
      float d;
      d = bflo(a.x)-bflo(b.x); acc += d*d;  d = bfhi(a.x)-bfhi(b.x); acc += d*d;
      d = bflo(a.y)-bflo(b.y); acc += d*d;  d = bfhi(a.y)-bfhi(b.y); acc += d*d;
      d = bflo(a.z)-bflo(b.z); acc += d*d;  d = bfhi(a.z)-bfhi(b.z); acc += d*d;
      d = bflo(a.w)-bflo(b.w); acc += d*d;  d = bfhi(a.w)-bfhi(b.w); acc += d*d;
    }
    vsum[h] = acc;
  }

  float4 lg;
  {
    float l[4];
    #pragma unroll
    for (int h = 0; h < 4; ++h){
      const float hw = log1pf(__expf(hwts[h]));   // softplus
      l[h] = C_SQRT83*sdot[h] + C_SQRT13*(b4[h] + bb[h]) + C_VEC*hw*vsum[h];
    }
    lg.x=l[0]; lg.y=l[1]; lg.z=l[2]; lg.w=l[3];
  }
  *(float4*)(logits + (size_t)p*4) = lg;
}

// ----------------------- per (node,head) softmax + pair ---------------------

__global__ __launch_bounds__(256) void k_soft(
    const float* __restrict__ logits, const unsigned* __restrict__ pz,
    const unsigned* __restrict__ row_off, float* __restrict__ out_pair, int n)
{
  const int t = blockIdx.x*256 + threadIdx.x;
  if (t >= n*4) return;
  const int i = t >> 2, h = t & 3;
  const int beg = (int)row_off[i], end = (int)row_off[i+1];

  float m = -3.4e38f;
  for (int p = beg; p < end; ++p) m = fmaxf(m, logits[(size_t)p*4 + h]);

  float ssum = 0.f;
  float acc[16];
  #pragma unroll
  for (int c=0;c<16;c++) acc[c]=0.f;

  for (int p = beg; p < end; ++p){
    const float w = __expf(logits[(size_t)p*4 + h] - m);
    ssum += w;
    const uint4* pr = (const uint4*)(pz + (size_t)p*8);
    const uint4 a = pr[0], b = pr[1];
    acc[ 0]+=w*bflo(a.x); acc[ 1]+=w*bfhi(a.x);
    acc[ 2]+=w*bflo(a.y); acc[ 3]+=w*bfhi(a.y);
    acc[ 4]+=w*bflo(a.z); acc[ 5]+=w*bfhi(a.z);
    acc[ 6]+=w*bflo(a.w); acc[ 7]+=w*bfhi(a.w);
    acc[ 8]+=w*bflo(b.x); acc[ 9]+=w*bfhi(b.x);
    acc[10]+=w*bflo(b.y); acc[11]+=w*bfhi(b.y);
    acc[12]+=w*bflo(b.z); acc[13]+=w*bfhi(b.z);
    acc[14]+=w*bflo(b.w); acc[15]+=w*bfhi(b.w);
  }
  const float inv = (end > beg) ? (1.f/ssum) : 0.f;
  float4* dst = (float4*)(out_pair + (size_t)i*64 + h*16);
  float4 o;
  o.x=acc[0]*inv;  o.y=acc[1]*inv;  o.z=acc[2]*inv;  o.w=acc[3]*inv;  dst[0]=o;
  o.x=acc[4]*inv;  o.y=acc[5]*inv;  o.z=acc[6]*inv;  o.w=acc[7]*inv;  dst[1]=o;
  o.x=acc[8]*inv;  o.y=acc[9]*inv;  o.z=acc[10]*inv; o.w=acc[11]*inv; dst[2]=o;
  o.x=acc[12]*inv; o.y=acc[13]*inv; o.z=acc[14]*inv; o.w=acc[15]*inv; dst[3]=o;
}

// --------------------- feats assembly + output GEMM ------------------------

__global__ __launch_bounds__(256) void k_out(
    const float* __restrict__ vs, const float* __restrict__ vv,
    const float* __restrict__ out_pair, const unsigned* __restrict__ row_off,
    const float* __restrict__ quat, const float* __restrict__ trans,
    const float* __restrict__ Wout, const float* __restrict__ bout,
    float* __restrict__ out, int n)
{
  __shared__ float feats[32][448];
  __shared__ int degs[32];
  const int tid = threadIdx.x;
  const int node0 = blockIdx.x*32;

  if (tid < 32){
    const int g = node0 + tid;
    degs[tid] = (g < n) ? (int)(row_off[g+1] - row_off[g]) : 1;
  }
  __syncthreads();

  // out_scalar == v_scalar (softmax weights sum to 1), 0 for empty segments
  for (int x = tid; x < 32*256; x += 256){
    const int nd = x >> 8, c = x & 255;
    const int g = node0 + nd;
    feats[nd][c] = (g < n && degs[nd] > 0) ? vs[(size_t)g*256 + c] : 0.f;
  }
  // out_pair
  for (int x = tid; x < 32*64; x += 256){
    const int nd = x >> 6, c = x & 63;
    const int g = node0 + nd;
    feats[nd][384 + c] = (g < n) ? out_pair[(size_t)g*64 + c] : 0.f;
  }
  // out_vec == raw local points; empty segment -> R^-1(-t)
  for (int x = tid; x < 32*32; x += 256){
    const int nd = x >> 5, pt = x & 31;
    const int g = node0 + nd;
    float X=0.f, Y=0.f, Z=0.f;
    if (g < n){
      if (degs[nd] > 0){
        X = vv[(size_t)g*96 + pt*3];
        Y = vv[(size_t)g*96 + pt*3 + 1];
        Z = vv[(size_t)g*96 + pt*3 + 2];
      } else {
        const float4 q4 = *(const float4*)(quat + (size_t)g*4);
        const float tx = trans[(size_t)g*3], ty = trans[(size_t)g*3+1], tz = trans[(size_t)g*3+2];
        quat_rot(q4.x, -q4.y, -q4.z, -q4.w, -tx, -ty, -tz, X, Y, Z);
      }
    }
    feats[nd][256 + pt] = X;
    feats[nd][288 + pt] = Y;
    feats[nd][320 + pt] = Z;
    feats[nd][352 + pt] = sqrtf(X*X + Y*Y + Z*Z + 1e-8f);
  }
  __syncthreads();

  // GEMM: each wave computes 8 nodes x 64 cols; Wout streamed coalesced.
  const int lane = tid & 63;
  const int wave = tid >> 6;
  float acc[8];
  #pragma unroll
  for (int q8=0;q8<8;q8++) acc[q8]=0.f;

  for (int k = 0; k < 448; ++k){
    const float wv = Wout[(size_t)k*64 + lane];
    #pragma unroll
    for (int q8 = 0; q8 < 8; ++q8)
      acc[q8] += feats[wave*8 + q8][k] * wv;
  }
  const float bo = bout[lane];
  #pragma unroll
  for (int q8 = 0; q8 < 8; ++q8){
    const int g = node0 + wave*8 + q8;
    if (g < n) out[(size_t)g*64 + lane] = acc[q8] + bo;
  }
}

// --------------------------------- launch ----------------------------------

extern "C" void kernel_launch(void* const* d_in, const int* in_sizes, int n_in,
                              void* d_out, int out_size, void* d_ws, size_t ws_size,
                              hipStream_t stream) {
  const float* s     = (const float*)d_in[0];
  const float* z     = (const float*)d_in[1];
  const int*   ei    = (const int*)  d_in[2];
  const float* quat  = (const float*)d_in[3];
  const float* trans = (const float*)d_in[4];
  const float* Wqs   = (const float*)d_in[5];
  const float* Wks   = (const float*)d_in[6];
  const float* Wvs   = (const float*)d_in[7];
  const float* Wqv   = (const float*)d_in[8];
  const float* Wkv   = (const float*)d_in[9];
  const float* Wvv   = (const float*)d_in[10];
  const float* Wb    = (const float*)d_in[11];
  const float* bb    = (const float*)d_in[12];
  const float* Wdz   = (const float*)d_in[13];
  const float* bdz   = (const float*)d_in[14];
  const float* hwts  = (const float*)d_in[15];
  const float* Wout  = (const float*)d_in[16];
  const float* bout  = (const float*)d_in[17];
  float* out = (float*)d_out;

  const int n  = in_sizes[0] / 64;   // 20000
  const int ne = in_sizes[1] / 64;   // 640000

  size_t off = 0;
  char* base = (char*)d_ws;
  auto take = [&](size_t bytes)->char* {
    char* p = base + off;
    off += (bytes + 255) & ~(size_t)255;
    return p;
  };
  unsigned* qs     = (unsigned*)take((size_t)n*512);    // bf16 N x 256
  unsigned* ks     = (unsigned*)take((size_t)n*512);    // bf16 N x 256
  unsigned* qvt    = (unsigned*)take((size_t)n*192);    // bf16 N x 96 (rot + t)
  unsigned* kvt    = (unsigned*)take((size_t)n*192);    // bf16 N x 96 (rot + t)
  float*    vs     = (float*)   take((size_t)n*1024);   // f32  N x 256
  float*    vv     = (float*)   take((size_t)n*384);    // f32  N x 96 (raw)
  float*    logits = (float*)   take((size_t)ne*16);    // f32  E x 4 (CSR order)
  unsigned* pz     = (unsigned*)take((size_t)ne*32);    // bf16 E x 16 (CSR order)
  unsigned* counts = (unsigned*)take((size_t)n*4);
  unsigned* roff   = (unsigned*)take((size_t)(n+1)*4);
  unsigned* cur    = (unsigned*)take((size_t)n*4);
  unsigned* si     = (unsigned*)take((size_t)ne*4);
  unsigned* sj     = (unsigned*)take((size_t)ne*4);
  unsigned* se     = (unsigned*)take((size_t)ne*4);
  float*    opair  = (float*)   take((size_t)n*256);    // f32  N x 64
  (void)ws_size; (void)n_in; (void)out_size;

  const int gbE = (ne + 255) / 256;
  const int gbN = (n  + 255) / 256;

  k_zero <<<gbN, 256, 0, stream>>>(counts, n);
  k_count<<<gbE, 256, 0, stream>>>(ei, counts, ne);
  k_scan <<<1,   256, 0, stream>>>(counts, roff, cur, n);
  k_fill <<<gbE, 256, 0, stream>>>(ei, cur, si, sj, se, ne);
  k_proj <<<(n + 63)/64, 256, 0, stream>>>(s, quat, trans, Wqs, Wks, Wvs, Wqv, Wkv, Wvv,
                                           qs, ks, vs, qvt, kvt, vv, n);
  k_edge <<<gbE, 256, 0, stream>>>(z, si, sj, se, Wb, bb, Wdz, bdz, hwts,
                                   qs, ks, qvt, kvt, logits, pz, ne);
  k_soft <<<(n*4 + 255)/256, 256, 0, stream>>>(logits, pz, roff, opair, n);
  k_out  <<<(n + 31)/32, 256, 0, stream>>>(vs, vv, opair, roff, quat, trans,
                                           Wout, bout, out, n);
}

// Round 2
// 688.090 us; speedup vs baseline: 1.6097x; 1.6097x over previous
//
#include <hip/hip_runtime.h>
#include <stdint.h>

// ---------------------------------------------------------------------------
// InvariantPointAttention, N=20000 nodes, E=640000 edges, H=4, S=64, QK=VD=8
//
// Pipeline (all on `stream`):
//   k_zero / k_count / k_scan / k_fill : CSR build (sort edges by dest i)
//   k_proj   : tiled per-node projections (32 nodes/block, LDS s-tile):
//                q_s,k_s (bf16 Nx256), q_v,k_v (rotated+translated bf16 Nx96),
//                v_s (f32 Nx256), v_loc (raw points f32 Nx96, PLANE layout)
//              NOTE: out_scalar == v_s and out_vec == raw v_loc exactly
//              (softmax weights sum to 1; R^-1(R(v)+t-t)=v).
//   k_edge   : per sorted edge: logits[4] (f32) + pair_z[16] (bf16), coalesced
//   k_soft   : per (node,head) two-pass softmax over CSR segment -> out_pair
//   k_out    : assemble feats[448] per node + feats @ Wout + bout -> out
// ---------------------------------------------------------------------------

#define C_SQRT83  1.6329931618554518f   // sqrt(8/3)
#define C_SQRT13  0.5773502691896258f   // sqrt(1/3)
#define C_VEC    -0.04811252243246881f  // -0.5*sqrt(1/108)

__device__ __forceinline__ unsigned short f2bf(float f){
  unsigned u = __float_as_uint(f);
  u += 0x7fffu + ((u >> 16) & 1u);          // round-to-nearest-even
  return (unsigned short)(u >> 16);
}
__device__ __forceinline__ unsigned pack2(float a, float b){
  return (unsigned)f2bf(a) | ((unsigned)f2bf(b) << 16);
}
__device__ __forceinline__ float bflo(unsigned u){ return __uint_as_float(u << 16); }
__device__ __forceinline__ float bfhi(unsigned u){ return __uint_as_float(u & 0xffff0000u); }

__device__ __forceinline__ void quat_rot(float w, float ux, float uy, float uz,
                                         float vx, float vy, float vz,
                                         float& ox, float& oy, float& oz){
  float cx = uy*vz - uz*vy;
  float cy = uz*vx - ux*vz;
  float cz = ux*vy - uy*vx;
  float dx = uy*cz - uz*cy;
  float dy = uz*cx - ux*cz;
  float dz = ux*cy - uy*cx;
  ox = vx + 2.f*(w*cx + dx);
  oy = vy + 2.f*(w*cy + dy);
  oz = vz + 2.f*(w*cz + dz);
}

// -------------------------------- CSR build --------------------------------

__global__ __launch_bounds__(256) void k_zero(unsigned* __restrict__ counts, int n){
  int g = blockIdx.x*256 + threadIdx.x;
  if (g < n) counts[g] = 0u;
}

__global__ __launch_bounds__(256) void k_count(const int* __restrict__ ei,
                                               unsigned* __restrict__ counts, int ne){
  int e = blockIdx.x*256 + threadIdx.x;
  if (e >= ne) return;
  atomicAdd(&counts[ei[e]], 1u);
}

__global__ __launch_bounds__(256) void k_scan(const unsigned* __restrict__ counts,
                                              unsigned* __restrict__ row_off,
                                              unsigned* __restrict__ cursor, int n){
  __shared__ unsigned part[256];
  int t = threadIdx.x;
  int chunk = (n + 255) >> 8;
  int s0 = t*chunk, s1 = min(s0 + chunk, n);
  unsigned sum = 0;
  for (int k = s0; k < s1; ++k) sum += counts[k];
  part[t] = sum; __syncthreads();
  for (int off = 1; off < 256; off <<= 1){
    unsigned v = (t >= off) ? part[t-off] : 0u;
    __syncthreads();
    part[t] += v;
    __syncthreads();
  }
  unsigned run = (t == 0) ? 0u : part[t-1];
  for (int k = s0; k < s1; ++k){
    row_off[k] = run; cursor[k] = run; run += counts[k];
  }
  if (t == 255) row_off[n] = part[255];
}

__global__ __launch_bounds__(256) void k_fill(const int* __restrict__ ei,
                                              unsigned* __restrict__ cursor,
                                              unsigned* __restrict__ si,
                                              unsigned* __restrict__ sj,
                                              unsigned* __restrict__ se, int ne){
  int e = blockIdx.x*256 + threadIdx.x;
  if (e >= ne) return;
  int i = ei[e];
  unsigned pos = atomicAdd(&cursor[i], 1u);
  si[pos] = (unsigned)i;
  sj[pos] = (unsigned)ei[ne + e];
  se[pos] = (unsigned)e;
}

// ------------------------------ node projections ----------------------------
// Block = 32 nodes, 256 threads.  s tile in LDS (broadcast reads).
// Scalar matrices (64x256): thread = (colgroup cg 0..63 of 4 cols, slice sl
// 0..3 of 8 nodes) -> 32 accumulators.  W float4 loads coalesced across lanes.
// Point matrices (64x96): thread = (cgp 0..31 [24 active], slp 0..7 of 4
// nodes) -> 16 accs; results staged in LDS for the x/y/z-plane -> per-point
// quat rotation remap.

#define BN 32

__device__ __forceinline__ void pass256(const float* __restrict__ W,
                                        const float st[BN][66], int cg, int sl,
                                        float acc[8][4]){
  #pragma unroll
  for (int i=0;i<8;i++){ acc[i][0]=0.f; acc[i][1]=0.f; acc[i][2]=0.f; acc[i][3]=0.f; }
  #pragma unroll 4
  for (int k = 0; k < 64; ++k){
    const float4 w = *(const float4*)(W + (size_t)k*256 + cg*4);
    #pragma unroll
    for (int i=0;i<8;i++){
      const float sv = st[sl*8+i][k];
      acc[i][0] += sv*w.x; acc[i][1] += sv*w.y; acc[i][2] += sv*w.z; acc[i][3] += sv*w.w;
    }
  }
}

__device__ __forceinline__ void pass96(const float* __restrict__ W,
                                       const float st[BN][66], int cgp, int slp,
                                       float acc[4][4]){
  #pragma unroll
  for (int i=0;i<4;i++){ acc[i][0]=0.f; acc[i][1]=0.f; acc[i][2]=0.f; acc[i][3]=0.f; }
  if (cgp >= 24) return;
  #pragma unroll 4
  for (int k = 0; k < 64; ++k){
    const float4 w = *(const float4*)(W + (size_t)k*96 + cgp*4);
    #pragma unroll
    for (int i=0;i<4;i++){
      const float sv = st[slp*4+i][k];
      acc[i][0] += sv*w.x; acc[i][1] += sv*w.y; acc[i][2] += sv*w.z; acc[i][3] += sv*w.w;
    }
  }
}

__global__ __launch_bounds__(256) void k_proj(
    const float* __restrict__ s, const float* __restrict__ quat, const float* __restrict__ trans,
    const float* __restrict__ Wqs, const float* __restrict__ Wks, const float* __restrict__ Wvs,
    const float* __restrict__ Wqv, const float* __restrict__ Wkv, const float* __restrict__ Wvv,
    unsigned* __restrict__ qs, unsigned* __restrict__ ks, float* __restrict__ vs,
    unsigned* __restrict__ qv, unsigned* __restrict__ kv, float* __restrict__ vv, int n)
{
  __shared__ float st[BN][66];     // s tile, padded
  __shared__ float pt[BN][97];     // point staging (x:0..31, y:32..63, z:64..95)
  const int tid = threadIdx.x;
  const int node0 = blockIdx.x * BN;

  // ---- load s tile (BN*64 f32 = 512 float4, 2 per thread) ----
  #pragma unroll
  for (int r = 0; r < 2; ++r){
    const int idx = tid + r*256;          // float4 index
    const int nd = idx >> 4, c4 = idx & 15;
    const int g = node0 + nd;
    float4 v = make_float4(0.f,0.f,0.f,0.f);
    if (g < n) v = *(const float4*)(s + (size_t)g*64 + c4*4);
    st[nd][c4*4+0]=v.x; st[nd][c4*4+1]=v.y; st[nd][c4*4+2]=v.z; st[nd][c4*4+3]=v.w;
  }
  __syncthreads();

  const int cg = tid & 63, sl = tid >> 6;     // scalar-pass mapping
  const int cgp = tid & 31, slp = tid >> 5;   // point-pass mapping
  float acc[8][4];

  // ---- q_scalar -> bf16 ----
  pass256(Wqs, st, cg, sl, acc);
  #pragma unroll
  for (int i=0;i<8;i++){
    const int g = node0 + sl*8 + i;
    if (g < n){
      uint2 u; u.x = pack2(acc[i][0],acc[i][1]); u.y = pack2(acc[i][2],acc[i][3]);
      *(uint2*)(qs + (size_t)g*128 + cg*2) = u;
    }
  }
  // ---- k_scalar -> bf16 ----
  pass256(Wks, st, cg, sl, acc);
  #pragma unroll
  for (int i=0;i<8;i++){
    const int g = node0 + sl*8 + i;
    if (g < n){
      uint2 u; u.x = pack2(acc[i][0],acc[i][1]); u.y = pack2(acc[i][2],acc[i][3]);
      *(uint2*)(ks + (size_t)g*128 + cg*2) = u;
    }
  }
  // ---- v_scalar -> f32 (== out_scalar) ----
  pass256(Wvs, st, cg, sl, acc);
  #pragma unroll
  for (int i=0;i<8;i++){
    const int g = node0 + sl*8 + i;
    if (g < n){
      float4 f; f.x=acc[i][0]; f.y=acc[i][1]; f.z=acc[i][2]; f.w=acc[i][3];
      *(float4*)(vs + (size_t)g*256 + cg*4) = f;
    }
  }

  // ---- point matrices ----
  float pac[4][4];

  // q_v: rotate + translate -> bf16
  pass96(Wqv, st, cgp, slp, pac);
  __syncthreads();
  if (cgp < 24){
    #pragma unroll
    for (int i=0;i<4;i++){
      #pragma unroll
      for (int c=0;c<4;c++) pt[slp*4+i][cgp*4+c] = pac[i][c];
    }
  }
  __syncthreads();
  #pragma unroll
  for (int r = 0; r < 2; ++r){
    const int t2 = tid + r*256;
    const int nd = t2 >> 4, pp = t2 & 15;     // point pair 2pp, 2pp+1
    const int g = node0 + nd;
    if (g < n){
      const float4 q4 = *(const float4*)(quat + (size_t)g*4);
      const float tx = trans[(size_t)g*3], ty = trans[(size_t)g*3+1], tz = trans[(size_t)g*3+2];
      float x0,y0,z0,x1,y1,z1;
      quat_rot(q4.x,q4.y,q4.z,q4.w, pt[nd][2*pp],   pt[nd][32+2*pp],   pt[nd][64+2*pp],   x0,y0,z0);
      quat_rot(q4.x,q4.y,q4.z,q4.w, pt[nd][2*pp+1], pt[nd][32+2*pp+1], pt[nd][64+2*pp+1], x1,y1,z1);
      x0+=tx; y0+=ty; z0+=tz; x1+=tx; y1+=ty; z1+=tz;
      unsigned* d = qv + (size_t)g*48 + pp*3;
      d[0] = pack2(x0,y0); d[1] = pack2(z0,x1); d[2] = pack2(y1,z1);
    }
  }

  // k_v: rotate + translate -> bf16
  pass96(Wkv, st, cgp, slp, pac);
  __syncthreads();
  if (cgp < 24){
    #pragma unroll
    for (int i=0;i<4;i++){
      #pragma unroll
      for (int c=0;c<4;c++) pt[slp*4+i][cgp*4+c] = pac[i][c];
    }
  }
  __syncthreads();
  #pragma unroll
  for (int r = 0; r < 2; ++r){
    const int t2 = tid + r*256;
    const int nd = t2 >> 4, pp = t2 & 15;
    const int g = node0 + nd;
    if (g < n){
      const float4 q4 = *(const float4*)(quat + (size_t)g*4);
      const float tx = trans[(size_t)g*3], ty = trans[(size_t)g*3+1], tz = trans[(size_t)g*3+2];
      float x0,y0,z0,x1,y1,z1;
      quat_rot(q4.x,q4.y,q4.z,q4.w, pt[nd][2*pp],   pt[nd][32+2*pp],   pt[nd][64+2*pp],   x0,y0,z0);
      quat_rot(q4.x,q4.y,q4.z,q4.w, pt[nd][2*pp+1], pt[nd][32+2*pp+1], pt[nd][64+2*pp+1], x1,y1,z1);
      x0+=tx; y0+=ty; z0+=tz; x1+=tx; y1+=ty; z1+=tz;
      unsigned* d = kv + (size_t)g*48 + pp*3;
      d[0] = pack2(x0,y0); d[1] = pack2(z0,x1); d[2] = pack2(y1,z1);
    }
  }

  // v_v: raw (pre-rotation) points == out_vec; store f32 in PLANE layout
  pass96(Wvv, st, cgp, slp, pac);
  __syncthreads();
  if (cgp < 24){
    #pragma unroll
    for (int i=0;i<4;i++){
      #pragma unroll
      for (int c=0;c<4;c++) pt[slp*4+i][cgp*4+c] = pac[i][c];
    }
  }
  __syncthreads();
  #pragma unroll
  for (int r = 0; r < 12; ++r){
    const int idx = tid + r*256;          // 0..3071
    const int nd = idx / 96, col = idx - nd*96;
    const int g = node0 + nd;
    if (g < n) vv[(size_t)g*96 + col] = pt[nd][col];
  }
}

// ------------------------------- edge kernel -------------------------------

__global__ __launch_bounds__(256) void k_edge(
    const float* __restrict__ z,
    const unsigned* __restrict__ si, const unsigned* __restrict__ sj, const unsigned* __restrict__ se,
    const float* __restrict__ Wb,  const float* __restrict__ bb,
    const float* __restrict__ Wdz, const float* __restrict__ bdz,
    const float* __restrict__ hwts,
    const unsigned* __restrict__ qs, const unsigned* __restrict__ ks,
    const unsigned* __restrict__ qv, const unsigned* __restrict__ kv,
    float* __restrict__ logits, unsigned* __restrict__ pz, int ne)
{
  const int p = blockIdx.x*256 + threadIdx.x;
  if (p >= ne) return;
  const unsigned i = si[p], j = sj[p], e = se[p];

  // ---- bias (z@Wb) and pair (z@Wdz) ----
  float b4[4];  b4[0]=b4[1]=b4[2]=b4[3]=0.f;
  float pacc[16];
  #pragma unroll
  for (int c=0;c<16;c++) pacc[c]=0.f;
  const float* zr = z + (size_t)e*64;
  #pragma unroll
  for (int k4 = 0; k4 < 16; ++k4){
    const float4 zv = *(const float4*)(zr + 4*k4);
    #pragma unroll
    for (int kk = 0; kk < 4; ++kk){
      const int k = 4*k4 + kk;
      const float zk = (kk==0)?zv.x:((kk==1)?zv.y:((kk==2)?zv.z:zv.w));
      const float4 wb = *(const float4*)(Wb + k*4);
      b4[0]+=zk*wb.x; b4[1]+=zk*wb.y; b4[2]+=zk*wb.z; b4[3]+=zk*wb.w;
      const float* wd = Wdz + k*16;
      const float4 w0=*(const float4*)(wd), w1=*(const float4*)(wd+4),
                   w2=*(const float4*)(wd+8), w3=*(const float4*)(wd+12);
      pacc[ 0]+=zk*w0.x; pacc[ 1]+=zk*w0.y; pacc[ 2]+=zk*w0.z; pacc[ 3]+=zk*w0.w;
      pacc[ 4]+=zk*w1.x; pacc[ 5]+=zk*w1.y; pacc[ 6]+=zk*w1.z; pacc[ 7]+=zk*w1.w;
      pacc[ 8]+=zk*w2.x; pacc[ 9]+=zk*w2.y; pacc[10]+=zk*w2.z; pacc[11]+=zk*w2.w;
      pacc[12]+=zk*w3.x; pacc[13]+=zk*w3.y; pacc[14]+=zk*w3.z; pacc[15]+=zk*w3.w;
    }
  }
  #pragma unroll
  for (int c=0;c<16;c++) pacc[c] += bdz[c];
  { uint4 u0, u1;
    u0.x=pack2(pacc[0],pacc[1]);   u0.y=pack2(pacc[2],pacc[3]);
    u0.z=pack2(pacc[4],pacc[5]);   u0.w=pack2(pacc[6],pacc[7]);
    u1.x=pack2(pacc[8],pacc[9]);   u1.y=pack2(pacc[10],pacc[11]);
    u1.z=pack2(pacc[12],pacc[13]); u1.w=pack2(pacc[14],pacc[15]);
    uint4* d = (uint4*)(pz + (size_t)p*8);
    d[0]=u0; d[1]=u1; }

  // ---- scalar attention dot: k_s[i] . q_s[j] per head ----
  const uint4* kr = (const uint4*)(ks + (size_t)i*128);
  const uint4* qr = (const uint4*)(qs + (size_t)j*128);
  float sdot[4];
  #pragma unroll
  for (int h = 0; h < 4; ++h){
    float acc = 0.f;
    #pragma unroll
    for (int c = 0; c < 8; ++c){
      const uint4 a = kr[h*8+c];
      const uint4 b = qr[h*8+c];
      acc += bflo(a.x)*bflo(b.x) + bfhi(a.x)*bfhi(b.x);
      acc += bflo(a.y)*bflo(b.y) + bfhi(a.y)*bfhi(b.y);
      acc += bflo(a.z)*bflo(b.z) + bfhi(a.z)*bfhi(b.z);
      acc += bflo(a.w)*bflo(b.w) + bfhi(a.w)*bfhi(b.w);
    }
    sdot[h] = acc;
  }

  // ---- vector attention: sum_p |q_v[i]-k_v[j]|^2 per head ----
  const uint4* qvr = (const uint4*)(qv + (size_t)i*48);
  const uint4* kvr = (const uint4*)(kv + (size_t)j*48);
  float vsum[4];
  #pragma unroll
  for (int h = 0; h < 4; ++h){
    float acc = 0.f;
    #pragma unroll
    for (int c = 0; c < 3; ++c){
      const uint4 a = qvr[h*3+c];
      const uint4 b = kvr[h*3+c];
      float d;
      d = bflo(a.x)-bflo(b.x); acc += d*d;  d = bfhi(a.x)-bfhi(b.x); acc += d*d;
      d = bflo(a.y)-bflo(b.y); acc += d*d;  d = bfhi(a.y)-bfhi(b.y); acc += d*d;
      d = bflo(a.z)-bflo(b.z); acc += d*d;  d = bfhi(a.z)-bfhi(b.z); acc += d*d;
      d = bflo(a.w)-bflo(b.w); acc += d*d;  d = bfhi(a.w)-bfhi(b.w); acc += d*d;
    }
    vsum[h] = acc;
  }

  float4 lg;
  {
    float l[4];
    #pragma unroll
    for (int h = 0; h < 4; ++h){
      const float hw = log1pf(__expf(hwts[h]));   // softplus
      l[h] = C_SQRT83*sdot[h] + C_SQRT13*(b4[h] + bb[h]) + C_VEC*hw*vsum[h];
    }
    lg.x=l[0]; lg.y=l[1]; lg.z=l[2]; lg.w=l[3];
  }
  *(float4*)(logits + (size_t)p*4) = lg;
}

// ----------------------- per (node,head) softmax + pair ---------------------

__global__ __launch_bounds__(256) void k_soft(
    const float* __restrict__ logits, const unsigned* __restrict__ pz,
    const unsigned* __restrict__ row_off, float* __restrict__ out_pair, int n)
{
  const int t = blockIdx.x*256 + threadIdx.x;
  if (t >= n*4) return;
  const int i = t >> 2, h = t & 3;
  const int beg = (int)row_off[i], end = (int)row_off[i+1];

  float m = -3.4e38f;
  for (int p = beg; p < end; ++p) m = fmaxf(m, logits[(size_t)p*4 + h]);

  float ssum = 0.f;
  float acc[16];
  #pragma unroll
  for (int c=0;c<16;c++) acc[c]=0.f;

  for (int p = beg; p < end; ++p){
    const float w = __expf(logits[(size_t)p*4 + h] - m);
    ssum += w;
    const uint4* pr = (const uint4*)(pz + (size_t)p*8);
    const uint4 a = pr[0], b = pr[1];
    acc[ 0]+=w*bflo(a.x); acc[ 1]+=w*bfhi(a.x);
    acc[ 2]+=w*bflo(a.y); acc[ 3]+=w*bfhi(a.y);
    acc[ 4]+=w*bflo(a.z); acc[ 5]+=w*bfhi(a.z);
    acc[ 6]+=w*bflo(a.w); acc[ 7]+=w*bfhi(a.w);
    acc[ 8]+=w*bflo(b.x); acc[ 9]+=w*bfhi(b.x);
    acc[10]+=w*bflo(b.y); acc[11]+=w*bfhi(b.y);
    acc[12]+=w*bflo(b.z); acc[13]+=w*bfhi(b.z);
    acc[14]+=w*bflo(b.w); acc[15]+=w*bfhi(b.w);
  }
  const float inv = (end > beg) ? (1.f/ssum) : 0.f;
  float4* dst = (float4*)(out_pair + (size_t)i*64 + h*16);
  float4 o;
  o.x=acc[0]*inv;  o.y=acc[1]*inv;  o.z=acc[2]*inv;  o.w=acc[3]*inv;  dst[0]=o;
  o.x=acc[4]*inv;  o.y=acc[5]*inv;  o.z=acc[6]*inv;  o.w=acc[7]*inv;  dst[1]=o;
  o.x=acc[8]*inv;  o.y=acc[9]*inv;  o.z=acc[10]*inv; o.w=acc[11]*inv; dst[2]=o;
  o.x=acc[12]*inv; o.y=acc[13]*inv; o.z=acc[14]*inv; o.w=acc[15]*inv; dst[3]=o;
}

// --------------------- feats assembly + output GEMM ------------------------

__global__ __launch_bounds__(256) void k_out(
    const float* __restrict__ vs, const float* __restrict__ vv,
    const float* __restrict__ out_pair, const unsigned* __restrict__ row_off,
    const float* __restrict__ quat, const float* __restrict__ trans,
    const float* __restrict__ Wout, const float* __restrict__ bout,
    float* __restrict__ out, int n)
{
  __shared__ float feats[32][448];
  __shared__ int degs[32];
  const int tid = threadIdx.x;
  const int node0 = blockIdx.x*32;

  if (tid < 32){
    const int g = node0 + tid;
    degs[tid] = (g < n) ? (int)(row_off[g+1] - row_off[g]) : 1;
  }
  __syncthreads();

  // out_scalar == v_scalar (softmax weights sum to 1), 0 for empty segments
  for (int x = tid; x < 32*256; x += 256){
    const int nd = x >> 8, c = x & 255;
    const int g = node0 + nd;
    feats[nd][c] = (g < n && degs[nd] > 0) ? vs[(size_t)g*256 + c] : 0.f;
  }
  // out_pair
  for (int x = tid; x < 32*64; x += 256){
    const int nd = x >> 6, c = x & 63;
    const int g = node0 + nd;
    feats[nd][384 + c] = (g < n) ? out_pair[(size_t)g*64 + c] : 0.f;
  }
  // out_vec == raw local points (vv is PLANE layout: x 0..31, y 32..63, z 64..95)
  for (int x = tid; x < 32*32; x += 256){
    const int nd = x >> 5, pt = x & 31;
    const int g = node0 + nd;
    float X=0.f, Y=0.f, Z=0.f;
    if (g < n){
      if (degs[nd] > 0){
        X = vv[(size_t)g*96 + pt];
        Y = vv[(size_t)g*96 + 32 + pt];
        Z = vv[(size_t)g*96 + 64 + pt];
      } else {
        const float4 q4 = *(const float4*)(quat + (size_t)g*4);
        const float tx = trans[(size_t)g*3], ty = trans[(size_t)g*3+1], tz = trans[(size_t)g*3+2];
        quat_rot(q4.x, -q4.y, -q4.z, -q4.w, -tx, -ty, -tz, X, Y, Z);
      }
    }
    feats[nd][256 + pt] = X;
    feats[nd][288 + pt] = Y;
    feats[nd][320 + pt] = Z;
    feats[nd][352 + pt] = sqrtf(X*X + Y*Y + Z*Z + 1e-8f);
  }
  __syncthreads();

  // GEMM: each wave computes 8 nodes x 64 cols; Wout streamed coalesced.
  const int lane = tid & 63;
  const int wave = tid >> 6;
  float acc[8];
  #pragma unroll
  for (int q8=0;q8<8;q8++) acc[q8]=0.f;

  for (int k = 0; k < 448; ++k){
    const float wv = Wout[(size_t)k*64 + lane];
    #pragma unroll
    for (int q8 = 0; q8 < 8; ++q8)
      acc[q8] += feats[wave*8 + q8][k] * wv;
  }
  const float bo = bout[lane];
  #pragma unroll
  for (int q8 = 0; q8 < 8; ++q8){
    const int g = node0 + wave*8 + q8;
    if (g < n) out[(size_t)g*64 + lane] = acc[q8] + bo;
  }
}

// --------------------------------- launch ----------------------------------

extern "C" void kernel_launch(void* const* d_in, const int* in_sizes, int n_in,
                              void* d_out, int out_size, void* d_ws, size_t ws_size,
                              hipStream_t stream) {
  const float* s     = (const float*)d_in[0];
  const float* z     = (const float*)d_in[1];
  const int*   ei    = (const int*)  d_in[2];
  const float* quat  = (const float*)d_in[3];
  const float* trans = (const float*)d_in[4];
  const float* Wqs   = (const float*)d_in[5];
  const float* Wks   = (const float*)d_in[6];
  const float* Wvs   = (const float*)d_in[7];
  const float* Wqv   = (const float*)d_in[8];
  const float* Wkv   = (const float*)d_in[9];
  const float* Wvv   = (const float*)d_in[10];
  const float* Wb    = (const float*)d_in[11];
  const float* bb    = (const float*)d_in[12];
  const float* Wdz   = (const float*)d_in[13];
  const float* bdz   = (const float*)d_in[14];
  const float* hwts  = (const float*)d_in[15];
  const float* Wout  = (const float*)d_in[16];
  const float* bout  = (const float*)d_in[17];
  float* out = (float*)d_out;

  const int n  = in_sizes[0] / 64;   // 20000
  const int ne = in_sizes[1] / 64;   // 640000

  size_t off = 0;
  char* base = (char*)d_ws;
  auto take = [&](size_t bytes)->char* {
    char* p = base + off;
    off += (bytes + 255) & ~(size_t)255;
    return p;
  };
  unsigned* qs     = (unsigned*)take((size_t)n*512);    // bf16 N x 256
  unsigned* ks     = (unsigned*)take((size_t)n*512);    // bf16 N x 256
  unsigned* qvt    = (unsigned*)take((size_t)n*192);    // bf16 N x 96 (rot + t)
  unsigned* kvt    = (unsigned*)take((size_t)n*192);    // bf16 N x 96 (rot + t)
  float*    vs     = (float*)   take((size_t)n*1024);   // f32  N x 256
  float*    vv     = (float*)   take((size_t)n*384);    // f32  N x 96 (raw, planes)
  float*    logits = (float*)   take((size_t)ne*16);    // f32  E x 4 (CSR order)
  unsigned* pz     = (unsigned*)take((size_t)ne*32);    // bf16 E x 16 (CSR order)
  unsigned* counts = (unsigned*)take((size_t)n*4);
  unsigned* roff   = (unsigned*)take((size_t)(n+1)*4);
  unsigned* cur    = (unsigned*)take((size_t)n*4);
  unsigned* si     = (unsigned*)take((size_t)ne*4);
  unsigned* sj     = (unsigned*)take((size_t)ne*4);
  unsigned* se     = (unsigned*)take((size_t)ne*4);
  float*    opair  = (float*)   take((size_t)n*256);    // f32  N x 64
  (void)ws_size; (void)n_in; (void)out_size;

  const int gbE = (ne + 255) / 256;
  const int gbN = (n  + 255) / 256;

  k_zero <<<gbN, 256, 0, stream>>>(counts, n);
  k_count<<<gbE, 256, 0, stream>>>(ei, counts, ne);
  k_scan <<<1,   256, 0, stream>>>(counts, roff, cur, n);
  k_fill <<<gbE, 256, 0, stream>>>(ei, cur, si, sj, se, ne);
  k_proj <<<(n + BN - 1)/BN, 256, 0, stream>>>(s, quat, trans, Wqs, Wks, Wvs, Wqv, Wkv, Wvv,
                                               qs, ks, vs, qvt, kvt, vv, n);
  k_edge <<<gbE, 256, 0, stream>>>(z, si, sj, se, Wb, bb, Wdz, bdz, hwts,
                                   qs, ks, qvt, kvt, logits, pz, ne);
  k_soft <<<(n*4 + 255)/256, 256, 0, stream>>>(logits, pz, roff, opair, n);
  k_out  <<<(n + 31)/32, 256, 0, stream>>>(vs, vv, opair, roff, quat, trans,
                                           Wout, bout, out, n);
}